// Round 17
// baseline (115.198 us; speedup 1.0000x reference)
//
#include <hip/hip_runtime.h>

typedef float f32x2 __attribute__((ext_vector_type(2)));
typedef f32x2 c32;   // [0]=re, [1]=im
typedef _Float16 f16x8 __attribute__((ext_vector_type(8)));
typedef float f32x4 __attribute__((ext_vector_type(4)));

__device__ __forceinline__ c32 mkc(float x, float y) { c32 r; r[0] = x; r[1] = y; return r; }

__device__ __forceinline__ c32 cmul(c32 a, c32 b) {
    c32 r;
    asm("v_pk_mul_f32 %0, %1, %2 op_sel:[0,0] op_sel_hi:[0,1]\n\t"
        "v_pk_fma_f32 %0, %1, %2, %0 op_sel:[1,1,0] op_sel_hi:[1,0,1] neg_lo:[1,0,0]"
        : "=&v"(r) : "v"(a), "v"(b));
    return r;
}
__device__ __forceinline__ c32 cmad(c32 a, c32 b, c32 acc) {
    asm("v_pk_fma_f32 %0, %1, %2, %0 op_sel:[0,0,0] op_sel_hi:[0,1,1]\n\t"
        "v_pk_fma_f32 %0, %1, %2, %0 op_sel:[1,1,0] op_sel_hi:[1,0,1] neg_lo:[1,0,0]"
        : "+v"(acc) : "v"(a), "v"(b));
    return acc;
}

// ---------------- gate-matrix build (verified) -----------------------------

__device__ __forceinline__ void mk_u3(float th, float ph, float la, c32 U[2][2]) {
    float ct = __cosf(0.5f * th), st = __sinf(0.5f * th);
    U[0][0] = mkc(ct, 0.f);
    U[0][1] = mkc(-__cosf(la) * st, -__sinf(la) * st);
    U[1][0] = mkc(__cosf(ph) * st, __sinf(ph) * st);
    U[1][1] = mkc(__cosf(ph + la) * ct, __sinf(ph + la) * ct);
}

__device__ __forceinline__ void lmul_kron(const c32 A[2][2], const c32 B[2][2], c32 m[4]) {
    c32 t[4];
#pragma unroll
    for (int r = 0; r < 4; ++r) {
        c32 acc = mkc(0.f, 0.f);
#pragma unroll
        for (int k = 0; k < 4; ++k)
            acc = cmad(cmul(A[r >> 1][k >> 1], B[r & 1][k & 1]), m[k], acc);
        t[r] = acc;
    }
#pragma unroll
    for (int r = 0; r < 4; ++r) m[r] = t[r];
}

__device__ void build_col(const float* __restrict__ w, int t, c32* gml) {
    const int g = t >> 2, c = t & 3;
    const float* p = w + g * 15;
    const int c0 = c >> 1, c1 = c & 1;
    c32 A[2][2], B[2][2], m[4], tmp;

    mk_u3(p[0], p[1], p[2], A);
    mk_u3(p[3], p[4], p[5], B);
#pragma unroll
    for (int r = 0; r < 4; ++r) m[r] = cmul(A[r >> 1][c0], B[r & 1][c1]);
    tmp = m[2]; m[2] = m[3]; m[3] = tmp;                 // CNOT(w0->w1)
    {
        float cc = __cosf(0.5f * p[6]), s = __sinf(0.5f * p[6]);
        A[0][0] = mkc(cc, 0.f); A[0][1] = mkc(-s, 0.f);
        A[1][0] = mkc(s, 0.f);  A[1][1] = mkc(cc, 0.f);
        float cz = __cosf(0.5f * p[7]), sz = __sinf(0.5f * p[7]);
        B[0][0] = mkc(cz, -sz); B[0][1] = mkc(0.f, 0.f);
        B[1][0] = mkc(0.f, 0.f); B[1][1] = mkc(cz, sz);
        lmul_kron(A, B, m);
    }
    tmp = m[1]; m[1] = m[3]; m[3] = tmp;                 // CNOT(w1->w0)
    {
        float cc = __cosf(0.5f * p[8]), s = __sinf(0.5f * p[8]);
        A[0][0] = mkc(cc, 0.f); A[0][1] = mkc(-s, 0.f);
        A[1][0] = mkc(s, 0.f);  A[1][1] = mkc(cc, 0.f);
        B[0][0] = mkc(1.f, 0.f); B[0][1] = mkc(0.f, 0.f);
        B[1][0] = mkc(0.f, 0.f); B[1][1] = mkc(1.f, 0.f);
        lmul_kron(A, B, m);
    }
    tmp = m[2]; m[2] = m[3]; m[3] = tmp;                 // CNOT(w0->w1)
    mk_u3(p[9], p[10], p[11], A);
    mk_u3(p[12], p[13], p[14], B);
    lmul_kron(A, B, m);
#pragma unroll
    for (int r = 0; r < 4; ++r) gml[g * 16 + r * 4 + c] = m[r];
}

__device__ __forceinline__ int cScat(int m) {
    return ((m & 8) << 4) | ((m & 4) << 2) | ((m & 2) << 2) | (m & 1);
}
__device__ __forceinline__ int dScat(int m) {
    return ((m & 8) << 4) | ((m & 4) << 3) | ((m & 2) << 2) | ((m & 1) << 1);
}

// ---------------- grid barrier (all 256 blocks co-resident: 1 block/CU) ----

__device__ __forceinline__ void grid_barrier(unsigned* cnt, unsigned nblk) {
    __syncthreads();
    if (threadIdx.x == 0) {
        __threadfence();   // release: publish this block's global stores
        __hip_atomic_fetch_add(cnt, 1u, __ATOMIC_ACQ_REL, __HIP_MEMORY_SCOPE_AGENT);
        while (__hip_atomic_load(cnt, __ATOMIC_ACQUIRE, __HIP_MEMORY_SCOPE_AGENT) < nblk)
            __builtin_amdgcn_s_sleep(8);
    }
    __syncthreads();
}

// ---------------- fused kernel: KA + bar + KB + bar + KC -------------------

__global__ __launch_bounds__(256) void fused_kernel(const float* __restrict__ x,
                                                    const float* __restrict__ w,
                                                    float* __restrict__ out,
                                                    c32* __restrict__ pass1cm,
                                                    c32* __restrict__ Ecm,
                                                    _Float16* __restrict__ U16,
                                                    unsigned* __restrict__ bar) {
    __shared__ __align__(16) char smem[21664];
    const int tid = threadIdx.x;
    const int bid = blockIdx.x;

    // ================= PHASE 1: windows + pass1/E (blocks 0..127) =========
    if (bid < 128) {
        c32* GML  = (c32*)smem;        // 80
        c32* bufA = GML + 80;          // 256
        c32* bufB = bufA + 256;        // 256
        c32* WIN  = bufB + 256;        // 5*256
        c32* kcol = WIN + 1280;        // 256
        c32* pcol = kcol + 256;        // 256  (total 2384 c32 = 19072 B)
        const int rr = tid >> 4, cc = tid & 15;

        if (tid < 20) build_col(w, tid, GML);
        __syncthreads();

        constexpr int gsM[19] = {0,0,0, 0,0, 1,1,1, 1,1, 2,2,2,2, 3,3,3,3, 4};
        constexpr int gsA[19] = {3,1,2, 2,0, 3,1,2, 2,0, 2,0,3,1, 2,0,3,1, 2};
        constexpr int gsB[19] = {2,0,1, 1,3, 2,0,1, 1,3, 1,3,2,0, 1,3,2,0, 0};
        constexpr int wEnd[5] = {3, 5, 8, 10, 19};

        c32* cur = bufA;
        c32* nxt = bufB;
        int stage = 0;
#pragma unroll 1
        for (int wm = 0; wm < 5; ++wm) {
            cur[tid] = mkc(rr == cc ? 1.f : 0.f, 0.f);
            __syncthreads();
#pragma unroll 1
            for (; stage < wEnd[wm]; ++stage) {
                const c32* mm = GML + gsM[stage] * 16;
                const int A = gsA[stage], B = gsB[stage];
                const int row = 2 * ((rr >> A) & 1) + ((rr >> B) & 1);
                const int base = rr & ~((1 << A) | (1 << B));
                c32 acc = cmul(mm[row * 4 + 0], cur[base * 16 + cc]);
                acc = cmad(mm[row * 4 + 1], cur[(base | (1 << B)) * 16 + cc], acc);
                acc = cmad(mm[row * 4 + 2], cur[(base | (1 << A)) * 16 + cc], acc);
                acc = cmad(mm[row * 4 + 3], cur[(base | (1 << A) | (1 << B)) * 16 + cc], acc);
                nxt[tid] = acc;
                __syncthreads();
                c32* t = cur; cur = nxt; nxt = t;
            }
            WIN[wm * 256 + tid] = cur[tid];
        }

        const int p = bid >> 6;                // 0: pass1, 1: pass2(+D-fold)
        const int jbase = (bid & 63) * 4;
        const c32* E16L = WIN + (p ? 2 : 0) * 256;
        const c32* C16L = WIN + (p ? 3 : 1) * 256;
        const c32* D16L = WIN + 4 * 256;

        const int i = tid;
        const int ci = (((i >> 7) & 1) << 3) | (((i >> 4) & 1) << 2) | (((i >> 3) & 1) << 1) | (i & 1);
        const int crest = i & 0x66;
        const int di = (((i >> 7) & 1) << 3) | (((i >> 5) & 1) << 2) | (((i >> 3) & 1) << 1) | ((i >> 1) & 1);
        const int drest = i & 0x55;

        for (int jj = 0; jj < 4; ++jj) {
            const int j = jbase + jj;
            __syncthreads();
            kcol[tid] = cmul(E16L[(tid >> 4) * 16 + (j >> 4)], E16L[(tid & 15) * 16 + (j & 15)]);
            __syncthreads();
            c32 val = mkc(0.f, 0.f);
#pragma unroll
            for (int m = 0; m < 16; ++m)
                val = cmad(C16L[ci * 16 + m], kcol[crest | cScat(m)], val);
            if (p == 0) {
                pass1cm[j * 256 + i] = val;
            } else {
                pcol[i] = val;
                __syncthreads();
                c32 e = mkc(0.f, 0.f);
#pragma unroll
                for (int m = 0; m < 16; ++m)
                    e = cmad(D16L[di * 16 + m], pcol[drest | dScat(m)], e);
                Ecm[j * 256 + i] = e;
            }
        }
    }
    grid_barrier(bar + 0, 256u);

    // ================= PHASE 2: U = E * pass1, fp16 (blocks 0..127) =======
    if (bid < 128) {
        c32* p0 = (c32*)smem;
        c32* p1 = p0 + 256;
        const int j0 = bid * 2;
        p0[tid] = pass1cm[j0 * 256 + tid];
        p1[tid] = pass1cm[(j0 + 1) * 256 + tid];
        __syncthreads();
        c32 a0 = mkc(0.f, 0.f), a1 = mkc(0.f, 0.f);
#pragma unroll 8
        for (int k = 0; k < 256; ++k) {
            c32 e = Ecm[k * 256 + tid];
            a0 = cmad(e, p0[k], a0);
            a1 = cmad(e, p1[k], a1);
        }
        U16[(size_t)tid * 256 + j0]             = (_Float16)a0[0];
        U16[(size_t)(tid + 256) * 256 + j0]     = (_Float16)a0[1];
        U16[(size_t)tid * 256 + j0 + 1]         = (_Float16)a1[0];
        U16[(size_t)(tid + 256) * 256 + j0 + 1] = (_Float16)a1[1];
    }
    grid_barrier(bar + 1, 256u);

    // ================= PHASE 3: GEMM + expectations (all blocks) ==========
    {
        _Float16 (*Bl)[264] = (_Float16(*)[264])smem;          // 16896 B
        float* nn = (float*)(smem + 16896);                    // 128 B
        float (*red)[2][16][9] = (float(*)[2][16][9])(smem + 17024); // 4608 B
        const int wave = tid >> 6, lane = tid & 63;
        const int bs = bid * 32;

        {
            const int n = tid >> 3, sub = tid & 7;
            const float4* xr = reinterpret_cast<const float4*>(x + (size_t)(bs + n) * 256 + sub * 32);
            float ssq = 0.f;
#pragma unroll
            for (int q = 0; q < 8; ++q) {
                float4 v = xr[q];
                ssq = fmaf(v.x, v.x, fmaf(v.y, v.y, fmaf(v.z, v.z, fmaf(v.w, v.w, ssq))));
                const int k0 = sub * 32 + q * 4;
                Bl[n][k0 + 0] = (_Float16)v.x;
                Bl[n][k0 + 1] = (_Float16)v.y;
                Bl[n][k0 + 2] = (_Float16)v.z;
                Bl[n][k0 + 3] = (_Float16)v.w;
            }
#pragma unroll
            for (int o = 4; o; o >>= 1) ssq += __shfl_xor(ssq, o, 64);
            if (sub == 0) nn[n] = ssq;
        }
        __syncthreads();

        f32x4 acc[2][4][2];
#pragma unroll
        for (int ri = 0; ri < 2; ++ri)
#pragma unroll
            for (int a = 0; a < 4; ++a)
#pragma unroll
                for (int nt = 0; nt < 2; ++nt) acc[ri][a][nt] = (f32x4){0.f, 0.f, 0.f, 0.f};

        const int ml = lane & 15, g = lane >> 4;
        const _Float16* Abase[2][4];
#pragma unroll
        for (int ri = 0; ri < 2; ++ri)
#pragma unroll
            for (int a = 0; a < 4; ++a)
                Abase[ri][a] = U16 + (size_t)(64 * wave + 16 * a + 256 * ri + ml) * 256 + g * 8;

#pragma unroll
        for (int kt = 0; kt < 8; ++kt) {
            f16x8 bf[2];
#pragma unroll
            for (int nt = 0; nt < 2; ++nt)
                bf[nt] = *reinterpret_cast<const f16x8*>(&Bl[nt * 16 + ml][kt * 32 + g * 8]);
#pragma unroll
            for (int ri = 0; ri < 2; ++ri)
#pragma unroll
                for (int a = 0; a < 4; ++a) {
                    f16x8 af = *reinterpret_cast<const f16x8*>(Abase[ri][a] + kt * 32);
#pragma unroll
                    for (int nt = 0; nt < 2; ++nt)
                        acc[ri][a][nt] = __builtin_amdgcn_mfma_f32_16x16x32_f16(af, bf[nt], acc[ri][a][nt], 0, 0, 0);
                }
        }

#pragma unroll
        for (int nt = 0; nt < 2; ++nt) {
            float E[9];
#pragma unroll
            for (int m = 0; m < 9; ++m) E[m] = 0.f;
#pragma unroll
            for (int a = 0; a < 4; ++a) {
#pragma unroll
                for (int r = 0; r < 4; ++r) {
                    float re = acc[0][a][nt][r], im = acc[1][a][nt][r];
                    float pr = re * re + im * im;
                    E[2] += (a & 2) ? -pr : pr;
                    E[5] += (r & 2) ? -pr : pr;
                    E[8] += ((a ^ r) & 2) ? -pr : pr;
                    if (a < 2) {
                        float pre = acc[0][a + 2][nt][r], pim = acc[1][a + 2][nt][r];
                        E[0] += 2.f * (re * pre + im * pim);
                        E[1] += 2.f * (re * pim - im * pre);
                        float dre = acc[0][a + 2][nt][r ^ 2], dim = acc[1][a + 2][nt][r ^ 2];
                        float dr = re * dre + im * dim;
                        E[6] += 2.f * dr;
                        E[7] += (r & 2) ? 2.f * dr : -2.f * dr;
                    }
                    if (!(r & 2)) {
                        float qre = acc[0][a][nt][r + 2], qim = acc[1][a][nt][r + 2];
                        E[3] += 2.f * (re * qre + im * qim);
                        E[4] += 2.f * (re * qim - im * qre);
                    }
                }
            }
#pragma unroll
            for (int m = 0; m < 9; ++m) {
                E[m] += __shfl_xor(E[m], 16, 64);
                E[m] += __shfl_xor(E[m], 32, 64);
                if (lane < 16) red[wave][nt][lane][m] = E[m];
            }
        }
        __syncthreads();

        if (tid < 32) {
            const int nt = tid >> 4, nc = tid & 15;
            const float innv = 1.0f / nn[tid];
#pragma unroll
            for (int m = 0; m < 9; ++m) {
                float e = red[0][nt][nc][m] + red[1][nt][nc][m] +
                          red[2][nt][nc][m] + red[3][nt][nc][m];
                out[(size_t)(bs + tid) * 9 + m] = e * innv;
            }
        }
    }
}

extern "C" void kernel_launch(void* const* d_in, const int* in_sizes, int n_in,
                              void* d_out, int out_size, void* d_ws, size_t ws_size,
                              hipStream_t stream) {
    const float* x = (const float*)d_in[0];
    const float* w = (const float*)d_in[1];
    float* out = (float*)d_out;

    unsigned* bar = (unsigned*)d_ws;               // 2 counters at byte 0
    c32* ws0      = (c32*)d_ws;
    c32* pass1cm  = ws0 + 2048;                    // byte 16384
    c32* Ecm      = ws0 + 2048 + 65536;
    _Float16* U16 = (_Float16*)(ws0 + 2048 + 2 * 65536);

    hipMemsetAsync(bar, 0, 64, stream);            // zero barrier counters each launch
    hipLaunchKernelGGL(fused_kernel, dim3(256), dim3(256), 0, stream,
                       x, w, out, pass1cm, Ecm, U16, bar);
}

// Round 18
// 33.657 us; speedup vs baseline: 3.4227x; 3.4227x over previous
//
#include <hip/hip_runtime.h>

typedef float f32x2 __attribute__((ext_vector_type(2)));
typedef f32x2 c32;   // [0]=re, [1]=im
typedef _Float16 f16x8 __attribute__((ext_vector_type(8)));
typedef float f32x4 __attribute__((ext_vector_type(4)));

__device__ __forceinline__ c32 mkc(float x, float y) { c32 r; r[0] = x; r[1] = y; return r; }

__device__ __forceinline__ c32 cmul(c32 a, c32 b) {
    c32 r;
    asm("v_pk_mul_f32 %0, %1, %2 op_sel:[0,0] op_sel_hi:[0,1]\n\t"
        "v_pk_fma_f32 %0, %1, %2, %0 op_sel:[1,1,0] op_sel_hi:[1,0,1] neg_lo:[1,0,0]"
        : "=&v"(r) : "v"(a), "v"(b));
    return r;
}
__device__ __forceinline__ c32 cmad(c32 a, c32 b, c32 acc) {
    asm("v_pk_fma_f32 %0, %1, %2, %0 op_sel:[0,0,0] op_sel_hi:[0,1,1]\n\t"
        "v_pk_fma_f32 %0, %1, %2, %0 op_sel:[1,1,0] op_sel_hi:[1,0,1] neg_lo:[1,0,0]"
        : "+v"(acc) : "v"(a), "v"(b));
    return acc;
}

// ---------------- gate-matrix build (verified, serial 20 threads) ----------

__device__ __forceinline__ void mk_u3(float th, float ph, float la, c32 U[2][2]) {
    float ct = __cosf(0.5f * th), st = __sinf(0.5f * th);
    U[0][0] = mkc(ct, 0.f);
    U[0][1] = mkc(-__cosf(la) * st, -__sinf(la) * st);
    U[1][0] = mkc(__cosf(ph) * st, __sinf(ph) * st);
    U[1][1] = mkc(__cosf(ph + la) * ct, __sinf(ph + la) * ct);
}

__device__ __forceinline__ void lmul_kron(const c32 A[2][2], const c32 B[2][2], c32 m[4]) {
    c32 t[4];
#pragma unroll
    for (int r = 0; r < 4; ++r) {
        c32 acc = mkc(0.f, 0.f);
#pragma unroll
        for (int k = 0; k < 4; ++k)
            acc = cmad(cmul(A[r >> 1][k >> 1], B[r & 1][k & 1]), m[k], acc);
        t[r] = acc;
    }
#pragma unroll
    for (int r = 0; r < 4; ++r) m[r] = t[r];
}

__device__ void build_col(const float* __restrict__ w, int t, c32* gml) {
    const int g = t >> 2, c = t & 3;
    const float* p = w + g * 15;
    const int c0 = c >> 1, c1 = c & 1;
    c32 A[2][2], B[2][2], m[4], tmp;

    mk_u3(p[0], p[1], p[2], A);
    mk_u3(p[3], p[4], p[5], B);
#pragma unroll
    for (int r = 0; r < 4; ++r) m[r] = cmul(A[r >> 1][c0], B[r & 1][c1]);
    tmp = m[2]; m[2] = m[3]; m[3] = tmp;                 // CNOT(w0->w1)
    {
        float cc = __cosf(0.5f * p[6]), s = __sinf(0.5f * p[6]);
        A[0][0] = mkc(cc, 0.f); A[0][1] = mkc(-s, 0.f);
        A[1][0] = mkc(s, 0.f);  A[1][1] = mkc(cc, 0.f);
        float cz = __cosf(0.5f * p[7]), sz = __sinf(0.5f * p[7]);
        B[0][0] = mkc(cz, -sz); B[0][1] = mkc(0.f, 0.f);
        B[1][0] = mkc(0.f, 0.f); B[1][1] = mkc(cz, sz);
        lmul_kron(A, B, m);
    }
    tmp = m[1]; m[1] = m[3]; m[3] = tmp;                 // CNOT(w1->w0)
    {
        float cc = __cosf(0.5f * p[8]), s = __sinf(0.5f * p[8]);
        A[0][0] = mkc(cc, 0.f); A[0][1] = mkc(-s, 0.f);
        A[1][0] = mkc(s, 0.f);  A[1][1] = mkc(cc, 0.f);
        B[0][0] = mkc(1.f, 0.f); B[0][1] = mkc(0.f, 0.f);
        B[1][0] = mkc(0.f, 0.f); B[1][1] = mkc(1.f, 0.f);
        lmul_kron(A, B, m);
    }
    tmp = m[2]; m[2] = m[3]; m[3] = tmp;                 // CNOT(w0->w1)
    mk_u3(p[9], p[10], p[11], A);
    mk_u3(p[12], p[13], p[14], B);
    lmul_kron(A, B, m);
#pragma unroll
    for (int r = 0; r < 4; ++r) gml[g * 16 + r * 4 + c] = m[r];
}

// ---------------- K1: build U column-wise, entry-parallel bar-gates --------
// 128 blocks x 256 threads; block owns columns j0=2*bid, j0+1.
// Standard amplitude indexing (qubit q <-> bit 7-q), R1-verified gate tables.
// Gate (p0,p1): out[i] = sum_k M[row(i)*4+k] * in[i with bits(p0,p1)<-k],
// row(i) = 2*bit_p0(i) + bit_p1(i), k = (bit_p0<<1)|bit_p1.

__global__ __launch_bounds__(256) void ubuild_kernel(const float* __restrict__ w,
                                                     _Float16* __restrict__ U16) {
    __shared__ c32 GML[80];
    __shared__ c32 buf[2][2][256];   // [pingpong][col][amp]
    const int tid = threadIdx.x;
    const int j0 = blockIdx.x * 2, j1 = j0 + 1;

    if (tid < 20) build_col(w, tid, GML);
    buf[0][0][tid] = mkc(tid == j0 ? 1.f : 0.f, 0.f);
    buf[0][1][tid] = mkc(tid == j1 ? 1.f : 0.f, 0.f);
    __syncthreads();

    constexpr int g_li[25] = {0,0,0,0,0,0,0,0, 1,1,1,1,1,1,1,1, 2,2,2,2, 3,3,3,3, 4};
    constexpr int g_p0[25] = {7,5,3,1,6,4,2,0, 7,5,3,1,6,4,2,0, 5,1,7,3, 5,1,7,3, 5};
    constexpr int g_p1[25] = {6,4,2,0,5,3,1,7, 6,4,2,0,5,3,1,7, 3,7,5,1, 3,7,5,1, 1};

    int pp = 0;
#pragma unroll 1
    for (int g = 0; g < 25; ++g) {
        const c32* M = GML + g_li[g] * 16;
        const int p0 = g_p0[g], p1 = g_p1[g];
        const int row = 2 * ((tid >> p0) & 1) + ((tid >> p1) & 1);
        const int base = tid & ~((1 << p0) | (1 << p1));
        const int i00 = base, i01 = base | (1 << p1), i10 = base | (1 << p0),
                  i11 = i10 | (1 << p1);
        c32 m0 = M[row * 4 + 0], m1 = M[row * 4 + 1],
            m2 = M[row * 4 + 2], m3 = M[row * 4 + 3];
#pragma unroll
        for (int c = 0; c < 2; ++c) {
            c32 a0 = buf[pp][c][i00], a1 = buf[pp][c][i01];
            c32 a2 = buf[pp][c][i10], a3 = buf[pp][c][i11];
            c32 r = cmul(m0, a0);
            r = cmad(m1, a1, r);
            r = cmad(m2, a2, r);
            r = cmad(m3, a3, r);
            buf[pp ^ 1][c][tid] = r;
        }
        __syncthreads();
        pp ^= 1;
    }

    // write columns: U16 row-major [512][256]; rows 0-255 Re, 256-511 Im
    c32 v0 = buf[pp][0][tid], v1 = buf[pp][1][tid];
    U16[(size_t)tid * 256 + j0]             = (_Float16)v0[0];
    U16[(size_t)(tid + 256) * 256 + j0]     = (_Float16)v0[1];
    U16[(size_t)tid * 256 + j1]             = (_Float16)v1[0];
    U16[(size_t)(tid + 256) * 256 + j1]     = (_Float16)v1[1];
}

// ---------------- K2: batch GEMM + expectations (verbatim, verified) -------

__global__ __launch_bounds__(256) void gemm_expect_kernel(const float* __restrict__ x,
                                                          const _Float16* __restrict__ U16,
                                                          float* __restrict__ out) {
    __shared__ _Float16 Bl[32][264];
    __shared__ float nn[32];
    __shared__ float red[4][2][16][9];
    const int tid = threadIdx.x;
    const int wave = tid >> 6, lane = tid & 63;
    const int bs = blockIdx.x * 32;

    {
        const int n = tid >> 3, sub = tid & 7;
        const float4* xr = reinterpret_cast<const float4*>(x + (size_t)(bs + n) * 256 + sub * 32);
        float ssq = 0.f;
#pragma unroll
        for (int q = 0; q < 8; ++q) {
            float4 v = xr[q];
            ssq = fmaf(v.x, v.x, fmaf(v.y, v.y, fmaf(v.z, v.z, fmaf(v.w, v.w, ssq))));
            const int k0 = sub * 32 + q * 4;
            Bl[n][k0 + 0] = (_Float16)v.x;
            Bl[n][k0 + 1] = (_Float16)v.y;
            Bl[n][k0 + 2] = (_Float16)v.z;
            Bl[n][k0 + 3] = (_Float16)v.w;
        }
#pragma unroll
        for (int o = 4; o; o >>= 1) ssq += __shfl_xor(ssq, o, 64);
        if (sub == 0) nn[n] = ssq;
    }
    __syncthreads();

    f32x4 acc[2][4][2];
#pragma unroll
    for (int ri = 0; ri < 2; ++ri)
#pragma unroll
        for (int a = 0; a < 4; ++a)
#pragma unroll
            for (int nt = 0; nt < 2; ++nt) acc[ri][a][nt] = (f32x4){0.f, 0.f, 0.f, 0.f};

    const int ml = lane & 15, g = lane >> 4;
    const _Float16* Abase[2][4];
#pragma unroll
    for (int ri = 0; ri < 2; ++ri)
#pragma unroll
        for (int a = 0; a < 4; ++a)
            Abase[ri][a] = U16 + (size_t)(64 * wave + 16 * a + 256 * ri + ml) * 256 + g * 8;

#pragma unroll
    for (int kt = 0; kt < 8; ++kt) {
        f16x8 bf[2];
#pragma unroll
        for (int nt = 0; nt < 2; ++nt)
            bf[nt] = *reinterpret_cast<const f16x8*>(&Bl[nt * 16 + ml][kt * 32 + g * 8]);
#pragma unroll
        for (int ri = 0; ri < 2; ++ri)
#pragma unroll
            for (int a = 0; a < 4; ++a) {
                f16x8 af = *reinterpret_cast<const f16x8*>(Abase[ri][a] + kt * 32);
#pragma unroll
                for (int nt = 0; nt < 2; ++nt)
                    acc[ri][a][nt] = __builtin_amdgcn_mfma_f32_16x16x32_f16(af, bf[nt], acc[ri][a][nt], 0, 0, 0);
            }
    }

#pragma unroll
    for (int nt = 0; nt < 2; ++nt) {
        float E[9];
#pragma unroll
        for (int m = 0; m < 9; ++m) E[m] = 0.f;
#pragma unroll
        for (int a = 0; a < 4; ++a) {
#pragma unroll
            for (int r = 0; r < 4; ++r) {
                float re = acc[0][a][nt][r], im = acc[1][a][nt][r];
                float pr = re * re + im * im;
                E[2] += (a & 2) ? -pr : pr;
                E[5] += (r & 2) ? -pr : pr;
                E[8] += ((a ^ r) & 2) ? -pr : pr;
                if (a < 2) {
                    float pre = acc[0][a + 2][nt][r], pim = acc[1][a + 2][nt][r];
                    E[0] += 2.f * (re * pre + im * pim);
                    E[1] += 2.f * (re * pim - im * pre);
                    float dre = acc[0][a + 2][nt][r ^ 2], dim = acc[1][a + 2][nt][r ^ 2];
                    float dr = re * dre + im * dim;
                    E[6] += 2.f * dr;
                    E[7] += (r & 2) ? 2.f * dr : -2.f * dr;
                }
                if (!(r & 2)) {
                    float qre = acc[0][a][nt][r + 2], qim = acc[1][a][nt][r + 2];
                    E[3] += 2.f * (re * qre + im * qim);
                    E[4] += 2.f * (re * qim - im * qre);
                }
            }
        }
#pragma unroll
        for (int m = 0; m < 9; ++m) {
            E[m] += __shfl_xor(E[m], 16, 64);
            E[m] += __shfl_xor(E[m], 32, 64);
            if (lane < 16) red[wave][nt][lane][m] = E[m];
        }
    }
    __syncthreads();

    if (tid < 32) {
        const int nt = tid >> 4, nc = tid & 15;
        const float innv = 1.0f / nn[tid];
#pragma unroll
        for (int m = 0; m < 9; ++m) {
            float e = red[0][nt][nc][m] + red[1][nt][nc][m] +
                      red[2][nt][nc][m] + red[3][nt][nc][m];
            out[(size_t)(bs + tid) * 9 + m] = e * innv;
        }
    }
}

extern "C" void kernel_launch(void* const* d_in, const int* in_sizes, int n_in,
                              void* d_out, int out_size, void* d_ws, size_t ws_size,
                              hipStream_t stream) {
    const float* x = (const float*)d_in[0];
    const float* w = (const float*)d_in[1];
    float* out = (float*)d_out;
    _Float16* U16 = (_Float16*)d_ws;   // 512*256 fp16 = 256 KB

    hipLaunchKernelGGL(ubuild_kernel, dim3(128), dim3(256), 0, stream, w, U16);

    const int batch = in_sizes[0] / 256;     // 8192
    hipLaunchKernelGGL(gemm_expect_kernel, dim3(batch / 32), dim3(256), 0, stream, x, U16, out);
}